// Round 1
// baseline (763.181 us; speedup 1.0000x reference)
//
#include <hip/hip_runtime.h>
#include <math.h>

// Problem constants
#define B_    128
#define R_    1152
#define C_    10
#define O_    16
#define I_    338
#define CO_   160          // C_*O_
#define SLAB  20480        // B_*CO_  (one r-slab of u_hat, contiguous)
#define KT    26           // K-tile; 338 = 13*26 exactly
#define NKT   13
#define XS_STRIDE 132      // 128 + 4 pad: keeps b128 alignment, breaks worst bank conflicts
#define WS_STRIDE 161      // 160 + 1 pad: conflict-free staging writes
#define RS_CHUNKS 16
#define R_PER_CHUNK 72     // 1152/16

// ---------------------------------------------------------------------------
// u_hat[b,r,c,o] = sum_i W[r,c,o,i] * x[b,r,i]
// One block per r: M=128(b) x N=160(c*16+o) x K=338 fp32 GEMM.
// Thread (tx=tid&15 -> o, ty=tid>>4 -> b/8) computes an 8(b) x 10(c) tile.
// u layout: u[r*SLAB + b*160 + c*16 + o]  (r-slab contiguous for streaming)
// ---------------------------------------------------------------------------
__global__ __launch_bounds__(256) void uhat_kernel(const float* __restrict__ x,
                                                   const float* __restrict__ W,
                                                   float* __restrict__ u) {
    __shared__ float xs[KT * XS_STRIDE];   // [k][b]
    __shared__ float wsh[KT * WS_STRIDE];  // [k][co]
    const int r   = blockIdx.x;
    const int tid = threadIdx.x;
    const int tx  = tid & 15;   // o
    const int ty  = tid >> 4;   // b group (0..15)

    float acc[8][10];
#pragma unroll
    for (int bb = 0; bb < 8; ++bb)
#pragma unroll
        for (int cc = 0; cc < 10; ++cc) acc[bb][cc] = 0.f;

    const float* xr = x + (size_t)r * I_;             // + b*R_*I_ later
    const float* wr = W + (size_t)r * CO_ * I_;

    for (int kt = 0; kt < NKT; ++kt) {
        const int k0 = kt * KT;
        // stage x tile: 128 rows x 26 (coalesced along i), transpose into [k][b]
#pragma unroll
        for (int it = 0; it < 13; ++it) {              // 13*256 == 128*26
            int i = tid + it * 256;
            int b = i / KT;
            int k = i - b * KT;
            xs[k * XS_STRIDE + b] = xr[(size_t)b * (R_ * I_) + k0 + k];
        }
        // stage W tile: 160 rows x 26 -> [k][co]
        for (int i = tid; i < CO_ * KT; i += 256) {
            int co = i / KT;
            int k  = i - co * KT;
            wsh[k * WS_STRIDE + co] = wr[(size_t)co * I_ + k0 + k];
        }
        __syncthreads();
        for (int k = 0; k < KT; ++k) {
            float xv[8], wv[10];
#pragma unroll
            for (int bb = 0; bb < 8; ++bb) xv[bb] = xs[k * XS_STRIDE + ty * 8 + bb];
#pragma unroll
            for (int cc = 0; cc < 10; ++cc) wv[cc] = wsh[k * WS_STRIDE + cc * 16 + tx];
#pragma unroll
            for (int bb = 0; bb < 8; ++bb)
#pragma unroll
                for (int cc = 0; cc < 10; ++cc)
                    acc[bb][cc] = fmaf(xv[bb], wv[cc], acc[bb][cc]);
        }
        __syncthreads();
    }

    float* ur = u + (size_t)r * SLAB;
#pragma unroll
    for (int bb = 0; bb < 8; ++bb)
#pragma unroll
        for (int cc = 0; cc < 10; ++cc)
            ur[(ty * 8 + bb) * CO_ + cc * 16 + tx] = acc[bb][cc];
}

// ---------------------------------------------------------------------------
// softmax over routes (axis r) per capsule c:  c_ij[r,c] = softmax_r(b_ij[r,c])
// ---------------------------------------------------------------------------
__global__ void softmax_kernel(const float* __restrict__ bij, float* __restrict__ cij) {
    const int c   = blockIdx.x;
    const int tid = threadIdx.x;
    __shared__ float redm[4];
    __shared__ float reds[4];
    __shared__ float bcast[2];

    float m = -1e30f;
    for (int r = tid; r < R_; r += 256) m = fmaxf(m, bij[r * C_ + c]);
#pragma unroll
    for (int off = 32; off > 0; off >>= 1) m = fmaxf(m, __shfl_down(m, off));
    if ((tid & 63) == 0) redm[tid >> 6] = m;
    __syncthreads();
    if (tid == 0) bcast[0] = fmaxf(fmaxf(redm[0], redm[1]), fmaxf(redm[2], redm[3]));
    __syncthreads();
    m = bcast[0];

    float s = 0.f;
    for (int r = tid; r < R_; r += 256) s += expf(bij[r * C_ + c] - m);
#pragma unroll
    for (int off = 32; off > 0; off >>= 1) s += __shfl_down(s, off);
    if ((tid & 63) == 0) reds[tid >> 6] = s;
    __syncthreads();
    if (tid == 0) bcast[1] = reds[0] + reds[1] + reds[2] + reds[3];
    __syncthreads();
    const float inv = 1.0f / bcast[1];
    for (int r = tid; r < R_; r += 256) cij[r * C_ + c] = expf(bij[r * C_ + c] - m) * inv;
}

// ---------------------------------------------------------------------------
// partial s over an r-chunk: partial[chunk, idx] = sum_{r in chunk} c_ij[r,c]*u[r,idx]
// idx = b*160 + c*16 + o. 16 chunks x 80 blocks -> enough waves to stream HBM.
// ---------------------------------------------------------------------------
__global__ void v_partial_kernel(const float* __restrict__ u, const float* __restrict__ cij,
                                 float* __restrict__ partial) {
    const int idx   = blockIdx.x * 256 + threadIdx.x;   // 0..20479
    const int chunk = blockIdx.y;
    const int c     = (idx >> 4) % 10;
    const int r0    = chunk * R_PER_CHUNK;
    const float* up = u + (size_t)r0 * SLAB + idx;
    const float* cp = cij + r0 * C_ + c;
    float s = 0.f;
#pragma unroll 4
    for (int rr = 0; rr < R_PER_CHUNK; ++rr)
        s = fmaf(cp[rr * C_], up[(size_t)rr * SLAB], s);
    partial[chunk * SLAB + idx] = s;
}

// sum partials -> s -> squash -> v  (v = s*|s|/(1+s^2), identical to ref formula)
__global__ void v_finalize_kernel(const float* __restrict__ partial, float* __restrict__ v) {
    const int idx = blockIdx.x * 256 + threadIdx.x;
    float s = 0.f;
#pragma unroll
    for (int ch = 0; ch < RS_CHUNKS; ++ch) s += partial[ch * SLAB + idx];
    v[idx] = s * fabsf(s) / (1.0f + s * s);
}

// ---------------------------------------------------------------------------
// agreement: b_ij[r,c] += (1/B) * sum_{b,o} u[r,b,c,o] * v[b,c,o]
// one block per r, (64 lanes) x (10 c). Each y-row is exactly one wave.
// ---------------------------------------------------------------------------
__global__ void agree_kernel(const float* __restrict__ u, const float* __restrict__ v,
                             float* __restrict__ bij) {
    const int r = blockIdx.x;
    const int l = threadIdx.x;   // 0..63
    const int c = threadIdx.y;   // 0..9
    const float* ur = u + (size_t)r * SLAB;
    float acc = 0.f;
#pragma unroll 4
    for (int k = l; k < B_ * O_; k += 64) {
        int b = k >> 4, o = k & 15;
        int off = b * CO_ + c * O_ + o;
        acc = fmaf(ur[off], v[off], acc);
    }
#pragma unroll
    for (int off = 32; off > 0; off >>= 1) acc += __shfl_down(acc, off);
    if (l == 0) bij[r * C_ + c] += acc * (1.0f / B_);
}

// ---------------------------------------------------------------------------
extern "C" void kernel_launch(void* const* d_in, const int* in_sizes, int n_in,
                              void* d_out, int out_size, void* d_ws, size_t ws_size,
                              hipStream_t stream) {
    const float* x = (const float*)d_in[0];   // (B,R,I)
    const float* W = (const float*)d_in[1];   // (R,C,O,I)
    float* out = (float*)d_out;               // (B,C,O,1) = 20480 floats

    // workspace carve-up (floats): ~96 MB total
    float* ws      = (float*)d_ws;
    float* u       = ws;                                 // R_*SLAB = 23,592,960
    float* bij     = u + (size_t)R_ * SLAB;              // 11,520
    float* cij     = bij + R_ * C_;                      // 11,520
    float* partial = cij + R_ * C_;                      // 16*20480
    float* v       = partial + RS_CHUNKS * SLAB;         // 20,480

    hipMemsetAsync(bij, 0, R_ * C_ * sizeof(float), stream);
    uhat_kernel<<<R_, 256, 0, stream>>>(x, W, u);

    for (int it = 0; it < 3; ++it) {
        softmax_kernel<<<C_, 256, 0, stream>>>(bij, cij);
        dim3 g(SLAB / 256, RS_CHUNKS);
        v_partial_kernel<<<g, 256, 0, stream>>>(u, cij, partial);
        float* vout = (it == 2) ? out : v;
        v_finalize_kernel<<<SLAB / 256, 256, 0, stream>>>(partial, vout);
        if (it < 2) agree_kernel<<<R_, dim3(64, 10), 0, stream>>>(u, v, bij);
    }
}